// Round 6
// baseline (272.385 us; speedup 1.0000x reference)
//
#include <hip/hip_runtime.h>
#include <math.h>

#define NN 100000
#define NE 1600000
#define CH  128
#define CO  18
#define NPB 256                        // nodes per bucket (dst >> 8)
#define NBUK ((NN + NPB - 1) / NPB)    // 391
#define EPB 4096                       // edges per k_bin block
#define NBB ((NE + EPB - 1) / EPB)     // 391

typedef unsigned int uint;
typedef unsigned short ushort;
typedef float floatx4 __attribute__((ext_vector_type(4)));
typedef short short8 __attribute__((ext_vector_type(8)));
typedef ushort ushort4v __attribute__((ext_vector_type(4)));

// ---- bf16 helpers ----
__device__ __forceinline__ float bf_lo(uint u) { return __uint_as_float(u << 16); }
__device__ __forceinline__ float bf_hi(uint u) { return __uint_as_float(u & 0xFFFF0000u); }
__device__ __forceinline__ ushort f2bf(float f) {
    uint u = __float_as_uint(f);
    u += 0x7FFFu + ((u >> 16) & 1u);        // RNE
    return (ushort)(u >> 16);
}
__device__ __forceinline__ uint pack_bf16(float a, float b) {
    return (uint)f2bf(a) | ((uint)f2bf(b) << 16);
}

// ---------------- binned CSR build ----------------

__global__ __launch_bounds__(256) void k_bhist(const int* __restrict__ dst,
                                               int* __restrict__ bcnt) {
    __shared__ int h[NBUK];
    int tid = threadIdx.x;
    for (int i = tid; i < NBUK; i += 256) h[i] = 0;
    __syncthreads();
    int e0 = blockIdx.x * EPB;
#pragma unroll
    for (int i = 0; i < EPB / 256; ++i) {
        int e = e0 + i * 256 + tid;
        if (e < NE) atomicAdd(&h[dst[e] >> 8], 1);
    }
    __syncthreads();
    for (int i = tid; i < NBUK; i += 256)
        if (h[i]) atomicAdd(&bcnt[i], h[i]);
}

__global__ __launch_bounds__(512) void k_bscan(const int* __restrict__ bcnt,
                                               int* __restrict__ bbase,
                                               int* __restrict__ bcur) {
    __shared__ int s[512];
    int tid = threadIdx.x;
    int c = (tid < NBUK) ? bcnt[tid] : 0;
    s[tid] = c;
    __syncthreads();
    for (int off = 1; off < 512; off <<= 1) {
        int t = (tid >= off) ? s[tid - off] : 0;
        __syncthreads();
        s[tid] += t;
        __syncthreads();
    }
    if (tid < NBUK) {
        int ex = s[tid] - c;
        bbase[tid] = ex;
        bcur[tid] = ex;
    }
    if (tid == NBUK) bbase[NBUK] = NE;
}

// packed record: (src << 8) | (dst & 255)   [src < 2^17 fits]
__global__ __launch_bounds__(256) void k_bin(const int* __restrict__ src,
                                             const int* __restrict__ dst,
                                             int* __restrict__ bcur,
                                             uint* __restrict__ etmp) {
    __shared__ int h[NBUK];
    __shared__ int base[NBUK];
    int tid = threadIdx.x;
    for (int i = tid; i < NBUK; i += 256) h[i] = 0;
    __syncthreads();

    int e0 = blockIdx.x * EPB;
    int sv[EPB / 256], dv[EPB / 256];
#pragma unroll
    for (int i = 0; i < EPB / 256; ++i) {
        int e = e0 + i * 256 + tid;
        if (e < NE) {
            sv[i] = src[e];
            dv[i] = dst[e];
            atomicAdd(&h[dv[i] >> 8], 1);
        } else {
            dv[i] = -1;
        }
    }
    __syncthreads();
    for (int i = tid; i < NBUK; i += 256)
        base[i] = h[i] ? atomicAdd(&bcur[i], h[i]) : 0;
    __syncthreads();
    for (int i = tid; i < NBUK; i += 256) h[i] = 0;
    __syncthreads();
#pragma unroll
    for (int i = 0; i < EPB / 256; ++i) {
        if (dv[i] >= 0) {
            int b = dv[i] >> 8;
            int pos = base[b] + atomicAdd(&h[b], 1);
            etmp[pos] = ((uint)sv[i] << 8) | ((uint)dv[i] & 255u);
        }
    }
}

__global__ __launch_bounds__(256) void k_pass2(const int* __restrict__ bbase,
                                               const uint* __restrict__ etmp,
                                               int* __restrict__ row_start,
                                               float* __restrict__ dinv,
                                               int* __restrict__ csr_src) {
    __shared__ int hist[NPB];
    __shared__ int s[NPB];
    __shared__ int cur[NPB];
    int tid = threadIdx.x;
    int b = blockIdx.x;
    int e0 = bbase[b], e1 = bbase[b + 1];

    hist[tid] = 0;
    __syncthreads();
    for (int e = e0 + tid; e < e1; e += 256)
        atomicAdd(&hist[etmp[e] & 255u], 1);
    __syncthreads();

    int c = hist[tid];
    s[tid] = c;
    __syncthreads();
    for (int off = 1; off < 256; off <<= 1) {
        int t = (tid >= off) ? s[tid - off] : 0;
        __syncthreads();
        s[tid] += t;
        __syncthreads();
    }
    int pfx = s[tid] - c;
    s[tid] = pfx;
    cur[tid] = 0;

    int node = b * NPB + tid;
    if (node < NN) {
        row_start[node] = e0 + pfx;
        dinv[node] = rsqrtf((float)c + 1.0f);
    }
    if (b == NBUK - 1 && tid == 0) row_start[NN] = NE;
    __syncthreads();

    for (int e = e0 + tid; e < e1; e += 256) {
        uint r = etmp[e];
        int n = (int)(r & 255u);
        int p = e0 + s[n] + atomicAdd(&cur[n], 1);
        csr_src[p] = (int)(r >> 8);
    }
}

// ------- weight prep: Wt[n][k]=bf16(W1[k][n]); W2t[n][k]=bf16(W2[k][n]) pad 32

__global__ __launch_bounds__(256) void k_wprep(const float* __restrict__ W1,
                                               const float* __restrict__ W2,
                                               ushort* __restrict__ Wt,
                                               ushort* __restrict__ W2t) {
    int t = blockIdx.x * 256 + threadIdx.x;   // 64 blocks
    if (t < 128 * 128) {
        int k = t >> 7, n = t & 127;
        Wt[n * 128 + k] = f2bf(W1[t]);
    }
    if (t < 32 * 128) {
        int n = t >> 7, k = t & 127;
        W2t[t] = (n < CO) ? f2bf(W2[k * CO + n]) : (ushort)0;
    }
}

// ------- GEMM1 (MFMA): h1(bf16) = x @ W1 -----------------------------------

__global__ __launch_bounds__(256, 2) void k_gemm1(const float* __restrict__ x,
                                                  const uint* __restrict__ Wtg,
                                                  ushort* __restrict__ h1s) {
    __shared__ ushort As[128 * 128];
    __shared__ ushort Bs[128 * 128];
    int tid = threadIdx.x;
    int row0 = blockIdx.x * 128;

    for (int i = 0; i < 32; ++i) {
        int j = i * 256 + tid;
        int n = j >> 6, ku = j & 63;
        int uidx = (n * 64 + ku) ^ ((n & 7) << 2);
        ((uint*)Bs)[uidx] = Wtg[j];
    }
    for (int i = 0; i < 16; ++i) {
        int flat = i * 256 + tid;
        int r = flat >> 5, c4 = flat & 31;
        int gr = row0 + r;
        float4 v = (gr < NN) ? ((const float4*)x)[(size_t)gr * 32 + c4]
                             : make_float4(0.f, 0.f, 0.f, 0.f);
        ushort4v p;
        p.x = f2bf(v.x); p.y = f2bf(v.y); p.z = f2bf(v.z); p.w = f2bf(v.w);
        int idx = (r * 128 + c4 * 4) ^ ((r & 7) << 3);
        *(ushort4v*)&As[idx] = p;
    }
    __syncthreads();

    int lane = tid & 63;
    int wave = tid >> 6;
    int wrow = wave * 32;
    int lr = lane & 15;
    int lk8 = (lane >> 4) * 8;

    floatx4 acc[2][8];
#pragma unroll
    for (int a = 0; a < 2; ++a)
#pragma unroll
        for (int b = 0; b < 8; ++b) acc[a][b] = (floatx4)(0.0f);

#pragma unroll
    for (int ks = 0; ks < 4; ++ks) {
        int k0 = ks * 32 + lk8;
        int r0r = wrow + lr;
        int r1r = wrow + 16 + lr;
        short8 a0 = *(const short8*)&As[(r0r * 128 + k0) ^ ((r0r & 7) << 3)];
        short8 a1 = *(const short8*)&As[(r1r * 128 + k0) ^ ((r1r & 7) << 3)];
#pragma unroll
        for (int nt = 0; nt < 8; ++nt) {
            int n = nt * 16 + lr;
            short8 bf = *(const short8*)&Bs[(n * 128 + k0) ^ ((n & 7) << 3)];
            acc[0][nt] = __builtin_amdgcn_mfma_f32_16x16x32_bf16(a0, bf, acc[0][nt], 0, 0, 0);
            acc[1][nt] = __builtin_amdgcn_mfma_f32_16x16x32_bf16(a1, bf, acc[1][nt], 0, 0, 0);
        }
    }

    int drow = (lane >> 4) * 4;
#pragma unroll
    for (int rt = 0; rt < 2; ++rt) {
#pragma unroll
        for (int i = 0; i < 4; ++i) {
            int gr = row0 + wrow + rt * 16 + drow + i;
            if (gr < NN) {
                size_t base = (size_t)gr * 128;
#pragma unroll
                for (int nt = 0; nt < 8; ++nt)
                    h1s[base + nt * 16 + lr] = f2bf(acc[rt][nt][i]);
            }
        }
    }
}

// ------- fused agg1 + gemm2 --------------------------------------------------
// Phase 1: 4 waves x 32 nodes: CSR gather (8-edge unroll) + self-loop + bias
//          + relu -> bf16 rows in swizzled LDS.
// Phase 2: MFMA h2[128][18] = As @ W2t (cols padded to 32).

__global__ __launch_bounds__(256, 2) void k_agg1_gemm2(
        const int* __restrict__ row_start, const int* __restrict__ csr_src,
        const float* __restrict__ dinv, const uint* __restrict__ h1u,
        const float* __restrict__ b1, const uint* __restrict__ W2tg,
        ushort* __restrict__ h2b) {
    __shared__ ushort As[128 * 128];   // 32 KB
    __shared__ ushort Bs[32 * 128];    // 8 KB
    int tid = threadIdx.x;
    int lane = tid & 63;
    int wave = tid >> 6;
    int row0 = blockIdx.x * 128;

    // stage W2t -> Bs swizzled (2048 uints)
    for (int j = tid; j < 2048; j += 256) {
        int n = j >> 6, ku = j & 63;
        ((uint*)Bs)[(n * 64 + ku) ^ ((n & 7) << 2)] = W2tg[j];
    }

    float2 bb = ((const float2*)b1)[lane];

    // ---- phase 1: aggregate 32 nodes per wave ----
    for (int t = 0; t < 32; ++t) {
        int r = wave * 32 + t;          // local row
        int i = row0 + r;
        uint outv = 0u;
        if (i < NN) {
            int r0 = row_start[i], r1 = row_start[i + 1];
            float di = dinv[i];
            float ax = 0.0f, ay = 0.0f;
            int j = r0;
            for (; j + 7 < r1; j += 8) {
                int s0 = csr_src[j],     s1 = csr_src[j + 1];
                int s2 = csr_src[j + 2], s3 = csr_src[j + 3];
                int s4 = csr_src[j + 4], s5 = csr_src[j + 5];
                int s6 = csr_src[j + 6], s7 = csr_src[j + 7];
                float w0 = dinv[s0] * di, w1 = dinv[s1] * di;
                float w2 = dinv[s2] * di, w3 = dinv[s3] * di;
                float w4 = dinv[s4] * di, w5 = dinv[s5] * di;
                float w6 = dinv[s6] * di, w7 = dinv[s7] * di;
                uint u0 = h1u[(size_t)s0 * 64 + lane];
                uint u1 = h1u[(size_t)s1 * 64 + lane];
                uint u2 = h1u[(size_t)s2 * 64 + lane];
                uint u3 = h1u[(size_t)s3 * 64 + lane];
                uint u4 = h1u[(size_t)s4 * 64 + lane];
                uint u5 = h1u[(size_t)s5 * 64 + lane];
                uint u6 = h1u[(size_t)s6 * 64 + lane];
                uint u7 = h1u[(size_t)s7 * 64 + lane];
                ax += w0 * bf_lo(u0) + w1 * bf_lo(u1) + w2 * bf_lo(u2) + w3 * bf_lo(u3)
                    + w4 * bf_lo(u4) + w5 * bf_lo(u5) + w6 * bf_lo(u6) + w7 * bf_lo(u7);
                ay += w0 * bf_hi(u0) + w1 * bf_hi(u1) + w2 * bf_hi(u2) + w3 * bf_hi(u3)
                    + w4 * bf_hi(u4) + w5 * bf_hi(u5) + w6 * bf_hi(u6) + w7 * bf_hi(u7);
            }
            for (; j < r1; ++j) {
                int s0 = csr_src[j];
                float w0 = dinv[s0] * di;
                uint u0 = h1u[(size_t)s0 * 64 + lane];
                ax += w0 * bf_lo(u0);
                ay += w0 * bf_hi(u0);
            }
            uint us = h1u[(size_t)i * 64 + lane];
            float di2 = di * di;
            float ox = fmaxf(ax + di2 * bf_lo(us) + bb.x, 0.0f);
            float oy = fmaxf(ay + di2 * bf_hi(us) + bb.y, 0.0f);
            outv = pack_bf16(ox, oy);
        }
        *(uint*)&As[(r * 128 + lane * 2) ^ ((r & 7) << 3)] = outv;
    }
    __syncthreads();

    // ---- phase 2: MFMA ----
    int lr = lane & 15;
    int lk8 = (lane >> 4) * 8;
    int wrow = wave * 32;
    floatx4 acc[2][2];
#pragma unroll
    for (int a = 0; a < 2; ++a)
#pragma unroll
        for (int b = 0; b < 2; ++b) acc[a][b] = (floatx4)(0.0f);

#pragma unroll
    for (int ks = 0; ks < 4; ++ks) {
        int k0 = ks * 32 + lk8;
        int r0r = wrow + lr;
        int r1r = wrow + 16 + lr;
        short8 a0 = *(const short8*)&As[(r0r * 128 + k0) ^ ((r0r & 7) << 3)];
        short8 a1 = *(const short8*)&As[(r1r * 128 + k0) ^ ((r1r & 7) << 3)];
#pragma unroll
        for (int nt = 0; nt < 2; ++nt) {
            int n = nt * 16 + lr;
            short8 bf = *(const short8*)&Bs[(n * 128 + k0) ^ ((n & 7) << 3)];
            acc[0][nt] = __builtin_amdgcn_mfma_f32_16x16x32_bf16(a0, bf, acc[0][nt], 0, 0, 0);
            acc[1][nt] = __builtin_amdgcn_mfma_f32_16x16x32_bf16(a1, bf, acc[1][nt], 0, 0, 0);
        }
    }

    int drow = (lane >> 4) * 4;
#pragma unroll
    for (int rt = 0; rt < 2; ++rt) {
#pragma unroll
        for (int i = 0; i < 4; ++i) {
            int gr = row0 + wrow + rt * 16 + drow + i;
            if (gr < NN) {
#pragma unroll
                for (int nt = 0; nt < 2; ++nt) {
                    int col = nt * 16 + lr;
                    if (col < CO)
                        h2b[(size_t)gr * CO + col] = f2bf(acc[rt][nt][i]);
                }
            }
        }
    }
}

// ------- agg2 (CSR gather, bf16) + self-loop + bias + log_softmax -----------

__global__ __launch_bounds__(256) void k_agg2(const int* __restrict__ row_start,
                                              const int* __restrict__ csr_src,
                                              const float* __restrict__ dinv,
                                              const uint* __restrict__ h2u,
                                              const float* __restrict__ b2,
                                              float* __restrict__ out) {
    int i = blockIdx.x * 256 + threadIdx.x;
    if (i >= NN) return;
    int r0 = row_start[i], r1 = row_start[i + 1];
    float di = dinv[i];
    float acc[CO];
#pragma unroll
    for (int j = 0; j < CO; ++j) acc[j] = 0.0f;

    for (int e = r0; e < r1; ++e) {
        int s = csr_src[e];
        float w = dinv[s] * di;
        const uint* hr = h2u + (size_t)s * 9;
#pragma unroll
        for (int j = 0; j < 9; ++j) {
            uint u = hr[j];
            acc[2 * j]     += w * bf_lo(u);
            acc[2 * j + 1] += w * bf_hi(u);
        }
    }

    float di2 = di * di;
    const uint* hi = h2u + (size_t)i * 9;
    float m = -1e30f;
#pragma unroll
    for (int j = 0; j < 9; ++j) {
        uint u = hi[j];
        acc[2 * j]     += di2 * bf_lo(u) + b2[2 * j];
        acc[2 * j + 1] += di2 * bf_hi(u) + b2[2 * j + 1];
    }
#pragma unroll
    for (int j = 0; j < CO; ++j) m = fmaxf(m, acc[j]);
    float sum = 0.0f;
#pragma unroll
    for (int j = 0; j < CO; ++j) sum += expf(acc[j] - m);
    float lse = logf(sum);
    float* op = out + (size_t)i * CO;
#pragma unroll
    for (int j = 0; j < CO; ++j) op[j] = acc[j] - m - lse;
}

// ---------------- launch ----------------

extern "C" void kernel_launch(void* const* d_in, const int* in_sizes, int n_in,
                              void* d_out, int out_size, void* d_ws, size_t ws_size,
                              hipStream_t stream) {
    const float* x  = (const float*)d_in[0];
    const int*   ei = (const int*)d_in[1];
    const float* W1 = (const float*)d_in[2];
    const float* b1 = (const float*)d_in[3];
    const float* W2 = (const float*)d_in[4];
    const float* b2 = (const float*)d_in[5];
    float* out = (float*)d_out;

    const int* src = ei;
    const int* dst = ei + NE;

    // workspace layout (~43 MB)
    uint* h1u  = (uint*)d_ws;                        // N*64 uints (bf16 pairs)
    uint* h2u  = h1u + (size_t)NN * 64;              // N*9
    float* dinv = (float*)(h2u + (size_t)NN * 9);    // N
    int* row_start = (int*)(dinv + NN);              // N+1
    int* csr_src   = row_start + NN + 1;             // E
    uint* etmp     = (uint*)(csr_src + NE);          // E packed records
    int* bcnt      = (int*)(etmp + NE);              // NBUK
    int* bbase     = bcnt + NBUK;                    // NBUK+1
    int* bcur      = bbase + NBUK + 1;               // NBUK
    ushort* Wt     = (ushort*)(bcur + NBUK);         // 128*128 bf16
    ushort* W2t    = Wt + 128 * 128;                 // 32*128 bf16

    hipMemsetAsync(bcnt, 0, NBUK * sizeof(int), stream);

    k_bhist<<<NBB, 256, 0, stream>>>(dst, bcnt);
    k_bscan<<<1, 512, 0, stream>>>(bcnt, bbase, bcur);
    k_bin<<<NBB, 256, 0, stream>>>(src, dst, bcur, etmp);
    k_pass2<<<NBUK, 256, 0, stream>>>(bbase, etmp, row_start, dinv, csr_src);

    k_wprep<<<64, 256, 0, stream>>>(W1, W2, Wt, W2t);
    k_gemm1<<<(NN + 127) / 128, 256, 0, stream>>>(x, (const uint*)Wt, (ushort*)h1u);
    k_agg1_gemm2<<<(NN + 127) / 128, 256, 0, stream>>>(row_start, csr_src, dinv,
                                                       h1u, b1, (const uint*)W2t,
                                                       (ushort*)h2u);
    k_agg2<<<(NN + 255) / 256, 256, 0, stream>>>(row_start, csr_src, dinv, h2u, b2, out);
}

// Round 7
// 247.008 us; speedup vs baseline: 1.1027x; 1.1027x over previous
//
#include <hip/hip_runtime.h>
#include <math.h>

#define NN 100000
#define NE 1600000
#define CH  128
#define CO  18
#define NPB 256                        // nodes per bucket (dst >> 8)
#define NBUK ((NN + NPB - 1) / NPB)    // 391
#define EPB 4096                       // edges per k_bin block
#define NBB ((NE + EPB - 1) / EPB)     // 391

typedef unsigned int uint;
typedef unsigned short ushort;
typedef float floatx4 __attribute__((ext_vector_type(4)));
typedef short short8 __attribute__((ext_vector_type(8)));
typedef ushort ushort4v __attribute__((ext_vector_type(4)));

// ---- bf16 helpers ----
__device__ __forceinline__ float bf_lo(uint u) { return __uint_as_float(u << 16); }
__device__ __forceinline__ float bf_hi(uint u) { return __uint_as_float(u & 0xFFFF0000u); }
__device__ __forceinline__ ushort f2bf(float f) {
    uint u = __float_as_uint(f);
    u += 0x7FFFu + ((u >> 16) & 1u);        // RNE
    return (ushort)(u >> 16);
}
__device__ __forceinline__ uint pack_bf16(float a, float b) {
    return (uint)f2bf(a) | ((uint)f2bf(b) << 16);
}

// ---------------- binned CSR build ----------------

__global__ __launch_bounds__(256) void k_bhist(const int* __restrict__ dst,
                                               int* __restrict__ bcnt) {
    __shared__ int h[NBUK];
    int tid = threadIdx.x;
    for (int i = tid; i < NBUK; i += 256) h[i] = 0;
    __syncthreads();
    int e0 = blockIdx.x * EPB;
#pragma unroll
    for (int i = 0; i < EPB / 256; ++i) {
        int e = e0 + i * 256 + tid;
        if (e < NE) atomicAdd(&h[dst[e] >> 8], 1);
    }
    __syncthreads();
    for (int i = tid; i < NBUK; i += 256)
        if (h[i]) atomicAdd(&bcnt[i], h[i]);
}

__global__ __launch_bounds__(512) void k_bscan(const int* __restrict__ bcnt,
                                               int* __restrict__ bbase,
                                               int* __restrict__ bcur) {
    __shared__ int s[512];
    int tid = threadIdx.x;
    int c = (tid < NBUK) ? bcnt[tid] : 0;
    s[tid] = c;
    __syncthreads();
    for (int off = 1; off < 512; off <<= 1) {
        int t = (tid >= off) ? s[tid - off] : 0;
        __syncthreads();
        s[tid] += t;
        __syncthreads();
    }
    if (tid < NBUK) {
        int ex = s[tid] - c;
        bbase[tid] = ex;
        bcur[tid] = ex;
    }
    if (tid == NBUK) bbase[NBUK] = NE;
}

// packed record: (src << 8) | (dst & 255)   [src < 2^17 fits]
__global__ __launch_bounds__(256) void k_bin(const int* __restrict__ src,
                                             const int* __restrict__ dst,
                                             int* __restrict__ bcur,
                                             uint* __restrict__ etmp) {
    __shared__ int h[NBUK];
    __shared__ int base[NBUK];
    int tid = threadIdx.x;
    for (int i = tid; i < NBUK; i += 256) h[i] = 0;
    __syncthreads();

    int e0 = blockIdx.x * EPB;
    int sv[EPB / 256], dv[EPB / 256];
#pragma unroll
    for (int i = 0; i < EPB / 256; ++i) {
        int e = e0 + i * 256 + tid;
        if (e < NE) {
            sv[i] = src[e];
            dv[i] = dst[e];
            atomicAdd(&h[dv[i] >> 8], 1);
        } else {
            dv[i] = -1;
        }
    }
    __syncthreads();
    for (int i = tid; i < NBUK; i += 256)
        base[i] = h[i] ? atomicAdd(&bcur[i], h[i]) : 0;
    __syncthreads();
    for (int i = tid; i < NBUK; i += 256) h[i] = 0;
    __syncthreads();
#pragma unroll
    for (int i = 0; i < EPB / 256; ++i) {
        if (dv[i] >= 0) {
            int b = dv[i] >> 8;
            int pos = base[b] + atomicAdd(&h[b], 1);
            etmp[pos] = ((uint)sv[i] << 8) | ((uint)dv[i] & 255u);
        }
    }
}

__global__ __launch_bounds__(256) void k_pass2(const int* __restrict__ bbase,
                                               const uint* __restrict__ etmp,
                                               int* __restrict__ row_start,
                                               float* __restrict__ dinv,
                                               int* __restrict__ csr_src) {
    __shared__ int hist[NPB];
    __shared__ int s[NPB];
    __shared__ int cur[NPB];
    int tid = threadIdx.x;
    int b = blockIdx.x;
    int e0 = bbase[b], e1 = bbase[b + 1];

    hist[tid] = 0;
    __syncthreads();
    for (int e = e0 + tid; e < e1; e += 256)
        atomicAdd(&hist[etmp[e] & 255u], 1);
    __syncthreads();

    int c = hist[tid];
    s[tid] = c;
    __syncthreads();
    for (int off = 1; off < 256; off <<= 1) {
        int t = (tid >= off) ? s[tid - off] : 0;
        __syncthreads();
        s[tid] += t;
        __syncthreads();
    }
    int pfx = s[tid] - c;
    s[tid] = pfx;
    cur[tid] = 0;

    int node = b * NPB + tid;
    if (node < NN) {
        row_start[node] = e0 + pfx;
        dinv[node] = rsqrtf((float)c + 1.0f);
    }
    if (b == NBUK - 1 && tid == 0) row_start[NN] = NE;
    __syncthreads();

    for (int e = e0 + tid; e < e1; e += 256) {
        uint r = etmp[e];
        int n = (int)(r & 255u);
        int p = e0 + s[n] + atomicAdd(&cur[n], 1);
        csr_src[p] = (int)(r >> 8);
    }
}

// ------- W1 prep: Wt[n][k] = bf16(W1[k][n]) --------------------------------

__global__ __launch_bounds__(256) void k_wprep(const float* __restrict__ W1,
                                               ushort* __restrict__ Wt) {
    int t = blockIdx.x * 256 + threadIdx.x;   // 64 blocks
    if (t < 128 * 128) {
        int k = t >> 7, n = t & 127;
        Wt[n * 128 + k] = f2bf(W1[t]);
    }
}

// ------- GEMM1 (MFMA): h1(bf16) = x @ W1 -----------------------------------

__global__ __launch_bounds__(256, 2) void k_gemm1(const float* __restrict__ x,
                                                  const uint* __restrict__ Wtg,
                                                  ushort* __restrict__ h1s) {
    __shared__ ushort As[128 * 128];
    __shared__ ushort Bs[128 * 128];
    int tid = threadIdx.x;
    int row0 = blockIdx.x * 128;

    for (int i = 0; i < 32; ++i) {
        int j = i * 256 + tid;
        int n = j >> 6, ku = j & 63;
        int uidx = (n * 64 + ku) ^ ((n & 7) << 2);
        ((uint*)Bs)[uidx] = Wtg[j];
    }
    for (int i = 0; i < 16; ++i) {
        int flat = i * 256 + tid;
        int r = flat >> 5, c4 = flat & 31;
        int gr = row0 + r;
        float4 v = (gr < NN) ? ((const float4*)x)[(size_t)gr * 32 + c4]
                             : make_float4(0.f, 0.f, 0.f, 0.f);
        ushort4v p;
        p.x = f2bf(v.x); p.y = f2bf(v.y); p.z = f2bf(v.z); p.w = f2bf(v.w);
        int idx = (r * 128 + c4 * 4) ^ ((r & 7) << 3);
        *(ushort4v*)&As[idx] = p;
    }
    __syncthreads();

    int lane = tid & 63;
    int wave = tid >> 6;
    int wrow = wave * 32;
    int lr = lane & 15;
    int lk8 = (lane >> 4) * 8;

    floatx4 acc[2][8];
#pragma unroll
    for (int a = 0; a < 2; ++a)
#pragma unroll
        for (int b = 0; b < 8; ++b) acc[a][b] = (floatx4)(0.0f);

#pragma unroll
    for (int ks = 0; ks < 4; ++ks) {
        int k0 = ks * 32 + lk8;
        int r0r = wrow + lr;
        int r1r = wrow + 16 + lr;
        short8 a0 = *(const short8*)&As[(r0r * 128 + k0) ^ ((r0r & 7) << 3)];
        short8 a1 = *(const short8*)&As[(r1r * 128 + k0) ^ ((r1r & 7) << 3)];
#pragma unroll
        for (int nt = 0; nt < 8; ++nt) {
            int n = nt * 16 + lr;
            short8 bf = *(const short8*)&Bs[(n * 128 + k0) ^ ((n & 7) << 3)];
            acc[0][nt] = __builtin_amdgcn_mfma_f32_16x16x32_bf16(a0, bf, acc[0][nt], 0, 0, 0);
            acc[1][nt] = __builtin_amdgcn_mfma_f32_16x16x32_bf16(a1, bf, acc[1][nt], 0, 0, 0);
        }
    }

    int drow = (lane >> 4) * 4;
#pragma unroll
    for (int rt = 0; rt < 2; ++rt) {
#pragma unroll
        for (int i = 0; i < 4; ++i) {
            int gr = row0 + wrow + rt * 16 + drow + i;
            if (gr < NN) {
                size_t base = (size_t)gr * 128;
#pragma unroll
                for (int nt = 0; nt < 8; ++nt)
                    h1s[base + nt * 16 + lr] = f2bf(acc[rt][nt][i]);
            }
        }
    }
}

// ------- agg1 (CSR gather, bf16 rows) + self-loop + bias + relu -> bf16 -----
// one wave per node, 8-edge unroll for memory-level parallelism

__global__ __launch_bounds__(256) void k_agg1(const int* __restrict__ row_start,
                                              const int* __restrict__ csr_src,
                                              const float* __restrict__ dinv,
                                              const uint* __restrict__ h1u,
                                              const float* __restrict__ b1,
                                              uint* __restrict__ h1ru) {
    int wave = threadIdx.x >> 6;
    int lane = threadIdx.x & 63;
    int i = blockIdx.x * 4 + wave;
    if (i >= NN) return;
    int r0 = row_start[i], r1 = row_start[i + 1];
    float di = dinv[i];
    float ax = 0.0f, ay = 0.0f;

    int j = r0;
    for (; j + 7 < r1; j += 8) {
        int s0 = csr_src[j],     s1 = csr_src[j + 1];
        int s2 = csr_src[j + 2], s3 = csr_src[j + 3];
        int s4 = csr_src[j + 4], s5 = csr_src[j + 5];
        int s6 = csr_src[j + 6], s7 = csr_src[j + 7];
        float w0 = dinv[s0] * di, w1 = dinv[s1] * di;
        float w2 = dinv[s2] * di, w3 = dinv[s3] * di;
        float w4 = dinv[s4] * di, w5 = dinv[s5] * di;
        float w6 = dinv[s6] * di, w7 = dinv[s7] * di;
        uint u0 = h1u[(size_t)s0 * 64 + lane];
        uint u1 = h1u[(size_t)s1 * 64 + lane];
        uint u2 = h1u[(size_t)s2 * 64 + lane];
        uint u3 = h1u[(size_t)s3 * 64 + lane];
        uint u4 = h1u[(size_t)s4 * 64 + lane];
        uint u5 = h1u[(size_t)s5 * 64 + lane];
        uint u6 = h1u[(size_t)s6 * 64 + lane];
        uint u7 = h1u[(size_t)s7 * 64 + lane];
        ax += w0 * bf_lo(u0) + w1 * bf_lo(u1) + w2 * bf_lo(u2) + w3 * bf_lo(u3)
            + w4 * bf_lo(u4) + w5 * bf_lo(u5) + w6 * bf_lo(u6) + w7 * bf_lo(u7);
        ay += w0 * bf_hi(u0) + w1 * bf_hi(u1) + w2 * bf_hi(u2) + w3 * bf_hi(u3)
            + w4 * bf_hi(u4) + w5 * bf_hi(u5) + w6 * bf_hi(u6) + w7 * bf_hi(u7);
    }
    for (; j < r1; ++j) {
        int s0 = csr_src[j];
        float w0 = dinv[s0] * di;
        uint u0 = h1u[(size_t)s0 * 64 + lane];
        ax += w0 * bf_lo(u0);
        ay += w0 * bf_hi(u0);
    }

    uint us = h1u[(size_t)i * 64 + lane];
    float2 bb = ((const float2*)b1)[lane];
    float di2 = di * di;
    float ox = fmaxf(ax + di2 * bf_lo(us) + bb.x, 0.0f);
    float oy = fmaxf(ay + di2 * bf_hi(us) + bb.y, 0.0f);
    h1ru[(size_t)i * 64 + lane] = pack_bf16(ox, oy);
}

// ------- GEMM2: h2b(bf16) = h1r(bf16) @ W2 ; rows padded to 12 uints (48B) --

__global__ __launch_bounds__(256, 2) void k_gemm2(const uint* __restrict__ h1ru,
                                                  const float* __restrict__ W2,
                                                  ushort* __restrict__ h2b) {
    __shared__ float xs[128][129];
    __shared__ float Ws[128 * 18];
    int row0 = blockIdx.x * 128;
    int tid = threadIdx.x;

    for (int i = tid; i < 128 * 18; i += 256) Ws[i] = W2[i];
    for (int i = tid; i < 128 * 64; i += 256) {
        int r = i >> 6, c2 = i & 63;
        int gr = row0 + r;
        uint u = (gr < NN) ? h1ru[(size_t)gr * 64 + c2] : 0u;
        xs[r][2 * c2]     = bf_lo(u);
        xs[r][2 * c2 + 1] = bf_hi(u);
    }
    __syncthreads();

    int rl   = tid & 127;
    int half = tid >> 7;
    int j0   = half * 9;
    float acc[9];
#pragma unroll
    for (int j = 0; j < 9; ++j) acc[j] = 0.0f;

#pragma unroll 4
    for (int k = 0; k < 128; ++k) {
        float xv = xs[rl][k];
#pragma unroll
        for (int j = 0; j < 9; ++j)
            acc[j] += xv * Ws[k * 18 + j0 + j];
    }
    int gr = row0 + rl;
    if (gr < NN) {
#pragma unroll
        for (int j = 0; j < 9; ++j)
            h2b[(size_t)gr * 24 + j0 + j] = f2bf(acc[j]);   // stride 24 ushorts
    }
}

// ------- agg2 (CSR gather, padded bf16 rows) + bias + log_softmax -----------
// 1 thread/node, 4-edge unroll, rows read as 2x uint4 + 1x uint

__device__ __forceinline__ void acc_row(float* acc, float w,
                                        uint4 a, uint4 b, uint c) {
    acc[0]  += w * bf_lo(a.x); acc[1]  += w * bf_hi(a.x);
    acc[2]  += w * bf_lo(a.y); acc[3]  += w * bf_hi(a.y);
    acc[4]  += w * bf_lo(a.z); acc[5]  += w * bf_hi(a.z);
    acc[6]  += w * bf_lo(a.w); acc[7]  += w * bf_hi(a.w);
    acc[8]  += w * bf_lo(b.x); acc[9]  += w * bf_hi(b.x);
    acc[10] += w * bf_lo(b.y); acc[11] += w * bf_hi(b.y);
    acc[12] += w * bf_lo(b.z); acc[13] += w * bf_hi(b.z);
    acc[14] += w * bf_lo(b.w); acc[15] += w * bf_hi(b.w);
    acc[16] += w * bf_lo(c);   acc[17] += w * bf_hi(c);
}

__global__ __launch_bounds__(256) void k_agg2(const int* __restrict__ row_start,
                                              const int* __restrict__ csr_src,
                                              const float* __restrict__ dinv,
                                              const uint* __restrict__ h2u,   // 12 uints/row
                                              const float* __restrict__ b2,
                                              float* __restrict__ out) {
    int i = blockIdx.x * 256 + threadIdx.x;
    if (i >= NN) return;
    int r0 = row_start[i], r1 = row_start[i + 1];
    float di = dinv[i];
    float acc[CO];
#pragma unroll
    for (int j = 0; j < CO; ++j) acc[j] = 0.0f;

    int e = r0;
    for (; e + 3 < r1; e += 4) {
        int s0 = csr_src[e],     s1 = csr_src[e + 1];
        int s2 = csr_src[e + 2], s3 = csr_src[e + 3];
        float w0 = dinv[s0] * di, w1 = dinv[s1] * di;
        float w2 = dinv[s2] * di, w3 = dinv[s3] * di;
        const uint4* p0 = (const uint4*)(h2u + (size_t)s0 * 12);
        const uint4* p1 = (const uint4*)(h2u + (size_t)s1 * 12);
        const uint4* p2 = (const uint4*)(h2u + (size_t)s2 * 12);
        const uint4* p3 = (const uint4*)(h2u + (size_t)s3 * 12);
        uint4 a0 = p0[0], b0 = p0[1]; uint c0 = ((const uint*)p0)[8];
        uint4 a1 = p1[0], b1v = p1[1]; uint c1 = ((const uint*)p1)[8];
        uint4 a2 = p2[0], b2v = p2[1]; uint c2 = ((const uint*)p2)[8];
        uint4 a3 = p3[0], b3v = p3[1]; uint c3 = ((const uint*)p3)[8];
        acc_row(acc, w0, a0, b0, c0);
        acc_row(acc, w1, a1, b1v, c1);
        acc_row(acc, w2, a2, b2v, c2);
        acc_row(acc, w3, a3, b3v, c3);
    }
    for (; e < r1; ++e) {
        int s = csr_src[e];
        float w = dinv[s] * di;
        const uint4* p = (const uint4*)(h2u + (size_t)s * 12);
        uint4 a = p[0], b = p[1]; uint c = ((const uint*)p)[8];
        acc_row(acc, w, a, b, c);
    }

    float di2 = di * di;
    const uint4* pi = (const uint4*)(h2u + (size_t)i * 12);
    uint4 ia = pi[0], ib = pi[1]; uint ic = ((const uint*)pi)[8];
    acc_row(acc, di2, ia, ib, ic);

    float m = -1e30f;
#pragma unroll
    for (int j = 0; j < CO; ++j) {
        acc[j] += b2[j];
        m = fmaxf(m, acc[j]);
    }
    float sum = 0.0f;
#pragma unroll
    for (int j = 0; j < CO; ++j) sum += expf(acc[j] - m);
    float lse = logf(sum);
    float* op = out + (size_t)i * CO;
#pragma unroll
    for (int j = 0; j < CO; ++j) op[j] = acc[j] - m - lse;
}

// ---------------- launch ----------------

extern "C" void kernel_launch(void* const* d_in, const int* in_sizes, int n_in,
                              void* d_out, int out_size, void* d_ws, size_t ws_size,
                              hipStream_t stream) {
    const float* x  = (const float*)d_in[0];
    const int*   ei = (const int*)d_in[1];
    const float* W1 = (const float*)d_in[2];
    const float* b1 = (const float*)d_in[3];
    const float* W2 = (const float*)d_in[4];
    const float* b2 = (const float*)d_in[5];
    float* out = (float*)d_out;

    const int* src = ei;
    const int* dst = ei + NE;

    // workspace layout (~73 MB)
    uint* h1u  = (uint*)d_ws;                        // N*64 uints (bf16 pairs)
    uint* h1ru = h1u + (size_t)NN * 64;              // N*64
    uint* h2u  = h1ru + (size_t)NN * 64;             // N*12 (18 bf16 + pad)
    float* dinv = (float*)(h2u + (size_t)NN * 12);   // N
    int* row_start = (int*)(dinv + NN);              // N+1
    int* csr_src   = row_start + NN + 1;             // E
    uint* etmp     = (uint*)(csr_src + NE);          // E packed records
    int* bcnt      = (int*)(etmp + NE);              // NBUK
    int* bbase     = bcnt + NBUK;                    // NBUK+1
    int* bcur      = bbase + NBUK + 1;               // NBUK
    ushort* Wt     = (ushort*)(bcur + NBUK);         // 128*128 bf16

    hipMemsetAsync(bcnt, 0, NBUK * sizeof(int), stream);

    k_bhist<<<NBB, 256, 0, stream>>>(dst, bcnt);
    k_bscan<<<1, 512, 0, stream>>>(bcnt, bbase, bcur);
    k_bin<<<NBB, 256, 0, stream>>>(src, dst, bcur, etmp);
    k_pass2<<<NBUK, 256, 0, stream>>>(bbase, etmp, row_start, dinv, csr_src);

    k_wprep<<<64, 256, 0, stream>>>(W1, Wt);
    k_gemm1<<<(NN + 127) / 128, 256, 0, stream>>>(x, (const uint*)Wt, (ushort*)h1u);
    k_agg1<<<(NN + 3) / 4, 256, 0, stream>>>(row_start, csr_src, dinv, h1u, b1, h1ru);
    k_gemm2<<<(NN + 127) / 128, 256, 0, stream>>>(h1ru, W2, (ushort*)h2u);
    k_agg2<<<(NN + 255) / 256, 256, 0, stream>>>(row_start, csr_src, dinv, h2u, b2, out);
}